// Round 3
// baseline (91.506 us; speedup 1.0000x reference)
//
#include <hip/hip_runtime.h>

// IndRNN recurrent-only: h_t = relu(h_{t-1} * w[hid] + x[t,b,hid]); h_0 = 0.
// x: [2048, 64, 512] f32. 32768 independent chains, serial over t.
// R3: each thread owns TWO adjacent chains -> float2 (8 B/lane) loads/stores,
// the coalescing sweet spot; halves VMEM instruction count and doubles
// in-flight bytes per wave (4-deep pipeline x 8 x 512 B = 16 KB/wave,
// 4 MB chip-wide). 16384 threads = 256 waves = 1 wave/CU (all CUs busy).
// Stores nontemporal so x (256 MiB = L3 size) stays L3-resident across replays.

constexpr int LEN     = 2048;
constexpr int BATCH   = 64;
constexpr int HIDDEN  = 512;
constexpr int STRIDE2 = BATCH * HIDDEN / 2;  // 16384 float2 per time step
constexpr int U       = 8;                   // steps per pipeline block
constexpr int NB      = LEN / U;             // 256 blocks

typedef float f2 __attribute__((ext_vector_type(2)));

__global__ __launch_bounds__(64) void indrnn_kernel(
    const float* __restrict__ x,
    const float* __restrict__ w,
    float* __restrict__ out)
{
    const int idx = blockIdx.x * blockDim.x + threadIdx.x;   // 0..16383
    const int hid0 = (2 * idx) & (HIDDEN - 1);               // even, <= 510
    const f2 wv = *(const f2*)(w + hid0);                    // w[hid0], w[hid0+1]

    const f2* xp = (const f2*)x + idx;
    f2* op = (f2*)out + idx;

    f2 bA[U], bB[U], bC[U], bD[U];
    f2 h; h.x = 0.0f; h.y = 0.0f;

#define LOADBLK(buf, tb)                                                     \
    _Pragma("unroll")                                                        \
    for (int j = 0; j < U; ++j)                                              \
        (buf)[j] = xp[(size_t)((tb) * U + j) * STRIDE2];

#define STEPBLK(buf, tb)                                                     \
    _Pragma("unroll")                                                        \
    for (int j = 0; j < U; ++j) {                                            \
        h.x = fmaxf(fmaf(h.x, wv.x, (buf)[j].x), 0.0f);                      \
        h.y = fmaxf(fmaf(h.y, wv.y, (buf)[j].y), 0.0f);                      \
        __builtin_nontemporal_store(h, op + (size_t)((tb) * U + j) * STRIDE2);\
    }

    // Prologue: fill the 4-deep pipeline.
    LOADBLK(bA, 0)
    LOADBLK(bB, 1)
    LOADBLK(bC, 2)
    LOADBLK(bD, 3)

    // Steady state: at each STEP's wait, younger ops = 24 loads + ~24 stores
    // = 48 <= vmcnt cap 63, so the compiler can emit counted waits.
    for (int tb = 0; tb < NB - 4; tb += 4) {
        STEPBLK(bA, tb)     LOADBLK(bA, tb + 4)
        STEPBLK(bB, tb + 1) LOADBLK(bB, tb + 5)
        STEPBLK(bC, tb + 2) LOADBLK(bC, tb + 6)
        STEPBLK(bD, tb + 3) LOADBLK(bD, tb + 7)
    }

    // Epilogue: drain the last 4 blocks.
    STEPBLK(bA, NB - 4)
    STEPBLK(bB, NB - 3)
    STEPBLK(bC, NB - 2)
    STEPBLK(bD, NB - 1)

#undef LOADBLK
#undef STEPBLK
}

extern "C" void kernel_launch(void* const* d_in, const int* in_sizes, int n_in,
                              void* d_out, int out_size, void* d_ws, size_t ws_size,
                              hipStream_t stream) {
    const float* x = (const float*)d_in[0];
    const float* w = (const float*)d_in[1];
    float* out = (float*)d_out;

    const int total = STRIDE2;         // 16384 threads (2 chains each)
    const int block = 64;
    const int grid  = total / block;   // 256 blocks -> 1 per CU

    indrnn_kernel<<<grid, block, 0, stream>>>(x, w, out);
}

// Round 4
// 88.338 us; speedup vs baseline: 1.0359x; 1.0359x over previous
//
#include <hip/hip_runtime.h>

// IndRNN recurrent-only: h_t = relu(h_{t-1} * w[hid] + x[t,b,hid]); h_0 = 0.
// 32768 independent chains, one thread each; serial over t (LEN=2048).
// Proven-best config (R2, 79.9 us): scalar f32 lanes, 512 blocks x 64 thr
// (2 waves/CU -> TLP), 4-deep x 8-step rotating register pipeline
// (counted waits at vmcnt(48) <= 63 cap, ~32 loads in flight per wave),
// nontemporal stores keep x (256 MiB = L3 size) L3-resident across replays.
// R3 showed float2 @ 1 wave/CU regresses (TLP loss) - do not re-vectorize.

constexpr int LEN    = 2048;
constexpr int BATCH  = 64;
constexpr int HIDDEN = 512;
constexpr int STRIDE = BATCH * HIDDEN;   // 32768 elements per time step
constexpr int U      = 8;                // elements per pipeline block
constexpr int NB     = LEN / U;          // 256 blocks

__global__ __launch_bounds__(64) void indrnn_kernel(
    const float* __restrict__ x,
    const float* __restrict__ w,
    float* __restrict__ out)
{
    const int idx = blockIdx.x * blockDim.x + threadIdx.x;  // 0..32767
    const float wv = w[idx & (HIDDEN - 1)];

    const float* xp = x + idx;
    float* op = out + idx;

    float bA[U], bB[U], bC[U], bD[U];
    float h = 0.0f;

#define LOADBLK(buf, tb)                                                     \
    _Pragma("unroll")                                                        \
    for (int j = 0; j < U; ++j)                                              \
        (buf)[j] = xp[(size_t)((tb) * U + j) * STRIDE];

#define STEPBLK(buf, tb)                                                     \
    _Pragma("unroll")                                                        \
    for (int j = 0; j < U; ++j) {                                            \
        h = fmaxf(fmaf(h, wv, (buf)[j]), 0.0f);                              \
        __builtin_nontemporal_store(h, op + (size_t)((tb) * U + j) * STRIDE);\
    }

    // Prologue: fill the 4-deep pipeline.
    LOADBLK(bA, 0)
    LOADBLK(bB, 1)
    LOADBLK(bC, 2)
    LOADBLK(bD, 3)

    // Steady state: compute block tb while blocks tb+1..tb+3 are in flight
    // and immediately re-issue the prefetch 4 blocks ahead.
    for (int tb = 0; tb < NB - 4; tb += 4) {
        STEPBLK(bA, tb)     LOADBLK(bA, tb + 4)
        STEPBLK(bB, tb + 1) LOADBLK(bB, tb + 5)
        STEPBLK(bC, tb + 2) LOADBLK(bC, tb + 6)
        STEPBLK(bD, tb + 3) LOADBLK(bD, tb + 7)
    }

    // Epilogue: drain the last 4 blocks.
    STEPBLK(bA, NB - 4)
    STEPBLK(bB, NB - 3)
    STEPBLK(bC, NB - 2)
    STEPBLK(bD, NB - 1)

#undef LOADBLK
#undef STEPBLK
}

extern "C" void kernel_launch(void* const* d_in, const int* in_sizes, int n_in,
                              void* d_out, int out_size, void* d_ws, size_t ws_size,
                              hipStream_t stream) {
    const float* x = (const float*)d_in[0];
    const float* w = (const float*)d_in[1];
    float* out = (float*)d_out;

    const int total = STRIDE;          // 32768 threads, one per chain
    const int block = 64;              // 512 blocks -> 2 waves/CU
    const int grid  = total / block;

    indrnn_kernel<<<grid, block, 0, stream>>>(x, w, out);
}